// Round 7
// baseline (190.144 us; speedup 1.0000x reference)
//
#include <hip/hip_runtime.h>
#include <stdint.h>

#define B_ 8
#define C_ 256
#define O_ 256
#define HW_ 4096

typedef _Float16 f16x8 __attribute__((ext_vector_type(8)));
typedef __attribute__((ext_vector_type(4))) float f32x4;

// ---------- prep: x (NCHW f32) -> xT (NHWC fp16, relu applied) ----------
__global__ __launch_bounds__(256) void k_nhwc(const float* __restrict__ x,
                                              _Float16* __restrict__ xT) {
    int bh = blockIdx.x;
    int b = bh & 7, h = bh >> 3;
    int t = threadIdx.x, px = t & 63, wg = t >> 6;
#pragma unroll
    for (int i = 0; i < 4; ++i) {
        int c0 = i * 64 + wg * 16;
        f16x8 va, vb;
#pragma unroll
        for (int j = 0; j < 8; ++j) {
            float f0 = x[((size_t)(b * C_ + c0 + j)) * HW_ + h * 64 + px];
            float f1 = x[((size_t)(b * C_ + c0 + 8 + j)) * HW_ + h * 64 + px];
            va[j] = (_Float16)fmaxf(f0, 0.f);
            vb[j] = (_Float16)fmaxf(f1, 0.f);
        }
        _Float16* dst = xT + ((size_t)((b * 64 + h) * 64 + px)) * C_ + c0;
        *reinterpret_cast<f16x8*>(dst) = va;
        *reinterpret_cast<f16x8*>(dst + 8) = vb;
    }
}

// ---------- prep: w_def -> fp16 MFMA A-frags [k2][q8][mfg16][lane64][8] ----------
__global__ void k_prep_wdef(const float* __restrict__ w_def, _Float16* __restrict__ wfrag) {
    int idx = blockIdx.x * 256 + threadIdx.x;
    if (idx >= 9 * 8 * 16 * 64) return;
    int lane = idx & 63;
    int mfg = (idx >> 6) & 15;
    int ccc = (idx >> 10) & 7;
    int k2 = idx >> 13;
    int o = mfg * 16 + (lane & 15);
    int cb = ccc * 32 + (lane >> 4) * 8;
    f16x8 pk;
#pragma unroll
    for (int j = 0; j < 8; ++j)
        pk[j] = (_Float16)w_def[(size_t)(o * C_ + cb + j) * 9 + k2];
    *reinterpret_cast<f16x8*>(wfrag + (size_t)idx * 8) = pk;
}

// ---------- prep: w_off -> fp16 MFMA A-frags (M pad 18->32) ----------
__global__ void k_prep_woffrag(const float* __restrict__ w_off, _Float16* __restrict__ wfr) {
    int idx = blockIdx.x * 256 + threadIdx.x;
    if (idx >= 9 * 8 * 2 * 64) return;
    int lane = idx & 63;
    int mfg = (idx >> 6) & 1;
    int ccc = (idx >> 7) & 7;
    int k2 = idx >> 10;
    int o = mfg * 16 + (lane & 15);
    int cb = ccc * 32 + (lane >> 4) * 8;
    f16x8 pk;
#pragma unroll
    for (int j = 0; j < 8; ++j)
        pk[j] = (o < 18) ? (_Float16)w_off[(size_t)(o * C_ + cb + j) * 9 + k2] : (_Float16)0.f;
    *reinterpret_cast<f16x8*>(wfr + (size_t)idx * 8) = pk;
}

// ---------- offset conv via MFMA, no LDS ----------
__global__ __launch_bounds__(256) void k_offconv4(const _Float16* __restrict__ xT,
                                                  const _Float16* __restrict__ wofr,
                                                  const float* __restrict__ b_off,
                                                  float* __restrict__ offs) {
    int bh = blockIdx.x;
    int b = bh & 7, h = bh >> 3;
    int tid = threadIdx.x, lane = tid & 63, wm = tid >> 6;
    int px = wm * 16 + (lane & 15);
    int chl = (lane >> 4) * 8;
    f32x4 acc0 = (f32x4){0.f, 0.f, 0.f, 0.f};
    f32x4 acc1 = (f32x4){0.f, 0.f, 0.f, 0.f};
    const _Float16* xb = xT + (size_t)b * HW_ * C_;
    for (int k2 = 0; k2 < 9; ++k2) {
        int y = h + k2 / 3 - 1;
        int xs = px + k2 % 3 - 1;
        bool v = ((unsigned)y < 64u) && ((unsigned)xs < 64u);
        int yc = y < 0 ? 0 : (y > 63 ? 63 : y);
        int xc = xs < 0 ? 0 : (xs > 63 ? 63 : xs);
        const _Float16* xp = xb + (size_t)(yc * 64 + xc) * C_ + chl;
#pragma unroll
        for (int q = 0; q < 8; ++q) {
            f16x8 bf = *reinterpret_cast<const f16x8*>(xp + q * 32);
            if (!v) bf = (f16x8)(_Float16)0.f;
            const f16x8* wp = reinterpret_cast<const f16x8*>(wofr) +
                              (size_t)((k2 * 8 + q) * 2) * 64 + lane;
            acc0 = __builtin_amdgcn_mfma_f32_16x16x32_f16(wp[0], bf, acc0, 0, 0, 0);
            acc1 = __builtin_amdgcn_mfma_f32_16x16x32_f16(wp[64], bf, acc1, 0, 0, 0);
        }
    }
#pragma unroll
    for (int r = 0; r < 4; ++r) {
        int oc = (lane >> 4) * 4 + r;
        offs[(((size_t)b * 18 + oc) * 64 + h) * 64 + px] = acc0[r] + b_off[oc];
    }
#pragma unroll
    for (int r = 0; r < 4; ++r) {
        int oc = 16 + (lane >> 4) * 4 + r;
        if (oc < 18)
            offs[(((size_t)b * 18 + oc) * 64 + h) * 64 + px] = acc1[r] + b_off[oc];
    }
}

// ---------- deform v7: register-direct B-frags, barrier-free tap loop ----------
// Block (b,h). Wave wm owns pixels wm*16..+15 and ALL 256 outputs.
// Lane role: pixel p = wm*16 + (lane&15), channel octet oc = lane>>4.
// The interpolated f16x8 IS the MFMA B-fragment (no LDS pack, no cross-wave sync).
__global__ __launch_bounds__(256, 2) void k_deform7(const _Float16* __restrict__ xT,
                                                    const _Float16* __restrict__ wfrag,
                                                    const float* __restrict__ offs,
                                                    float* __restrict__ out) {
    int blk = blockIdx.x;
    int b = blk & 7, h = blk >> 3;
    int tid = threadIdx.x, lane = tid & 63, wm = tid >> 6;

    // geometry, pre-unpacked: per (tap, pixel)
    __shared__ unsigned s_w00[576], s_w01[576], s_w10[576], s_w11[576];  // f16 dup-packed
    __shared__ unsigned s_xx[576];  // x0c | x1c<<16
    __shared__ unsigned s_yy[576];  // y0c | y1c<<8 | flag<<16 (flag=ry0 in [0,5], else 255)
    __shared__ __align__(16) _Float16 s_x[7 * 64 * 40];  // rows h-3..h+3, 80B px-stride

    const _Float16* xb = xT + (size_t)b * HW_ * C_;

    // ---- phase 0: geometry ----
    for (int idx = tid; idx < 576; idx += 256) {
        int k2 = idx >> 6, p = idx & 63;
        float dy = offs[(((size_t)b * 18 + k2 * 2 + 0) * 64 + h) * 64 + p];
        float dx = offs[(((size_t)b * 18 + k2 * 2 + 1) * 64 + h) * 64 + p];
        float py = (float)(h - 1 + k2 / 3) + dy;
        float pxx = (float)(p - 1 + k2 % 3) + dx;
        float y0f = floorf(py), x0f = floorf(pxx);
        float wy = py - y0f, wx = pxx - x0f;
        int y0 = (int)y0f, x0 = (int)x0f;
        float w00 = (1.f - wy) * (1.f - wx), w01 = (1.f - wy) * wx;
        float w10 = wy * (1.f - wx), w11 = wy * wx;
        bool vy0 = (unsigned)y0 < 64u, vy1 = (unsigned)(y0 + 1) < 64u;
        bool vx0 = (unsigned)x0 < 64u, vx1 = (unsigned)(x0 + 1) < 64u;
        if (!(vy0 && vx0)) w00 = 0.f;
        if (!(vy0 && vx1)) w01 = 0.f;
        if (!(vy1 && vx0)) w10 = 0.f;
        if (!(vy1 && vx1)) w11 = 0.f;
        union { _Float16 h[2]; unsigned u; } cv;
#define DUP(W) (cv.h[0] = (_Float16)(W), cv.h[1] = cv.h[0], cv.u)
        s_w00[idx] = DUP(w00);
        s_w01[idx] = DUP(w01);
        s_w10[idx] = DUP(w10);
        s_w11[idx] = DUP(w11);
#undef DUP
        int x0c = x0 < 0 ? 0 : (x0 > 63 ? 63 : x0);
        int x1c = (x0 + 1) < 0 ? 0 : ((x0 + 1) > 63 ? 63 : (x0 + 1));
        int y0c = y0 < 0 ? 0 : (y0 > 63 ? 63 : y0);
        int y1c = (y0 + 1) < 0 ? 0 : ((y0 + 1) > 63 ? 63 : (y0 + 1));
        int ry0 = y0 - (h - 3);
        unsigned flag = (ry0 >= 0 && ry0 <= 5) ? (unsigned)ry0 : 255u;
        s_xx[idx] = (unsigned)x0c | ((unsigned)x1c << 16);
        s_yy[idx] = (unsigned)y0c | ((unsigned)y1c << 8) | (flag << 16);
    }

    f32x4 acc[16];
#pragma unroll
    for (int i = 0; i < 16; ++i) acc[i] = (f32x4){0.f, 0.f, 0.f, 0.f};

    // ---- staging (T14 split: load early into regs, write after barrier) ----
    int spx = tid >> 2, so = tid & 3;
    f16x8 st[7];
#define STAGE_LOAD(CQ)                                                             \
    {                                                                              \
        _Pragma("unroll") for (int r = 0; r < 7; ++r)                              \
        {                                                                          \
            int yr = h - 3 + r;                                                    \
            yr = yr < 0 ? 0 : (yr > 63 ? 63 : yr);                                 \
            st[r] = *reinterpret_cast<const f16x8*>(                               \
                xb + (size_t)(yr * 64 + spx) * C_ + (CQ) * 32 + so * 8);           \
        }                                                                          \
    }
#define STAGE_WRITE()                                                              \
    {                                                                              \
        _Pragma("unroll") for (int r = 0; r < 7; ++r)                              \
            *reinterpret_cast<f16x8*>(&s_x[(r * 64 + spx) * 40 + so * 8]) = st[r]; \
    }

    STAGE_LOAD(0);
    STAGE_WRITE();
    asm volatile("s_waitcnt lgkmcnt(0)" ::: "memory");
    __builtin_amdgcn_s_barrier();

    int pl = lane & 15;       // pixel within wave group
    int oc8 = (lane >> 4) * 8;  // channel octet offset

    for (int cq = 0; cq < 8; ++cq) {
        if (cq < 7) STAGE_LOAD(cq + 1);  // in flight under the 9 taps

#pragma unroll
        for (int k2 = 0; k2 < 9; ++k2) {
            int g = k2 * 64 + wm * 16 + pl;
            union { unsigned u; _Float16 h[2]; } uw0, uw1, uw2, uw3;
            uw0.u = s_w00[g]; uw1.u = s_w01[g]; uw2.u = s_w10[g]; uw3.u = s_w11[g];
            unsigned xx = s_xx[g], yy = s_yy[g];
            int x0c = xx & 0xFFFF, x1c = xx >> 16;
            int flag = yy >> 16;
            f16x8 c00, c01, c10, c11;
            if (flag <= 5) {
                const _Float16* base0 = s_x + flag * 2560 + oc8;
                c00 = *reinterpret_cast<const f16x8*>(base0 + x0c * 40);
                c01 = *reinterpret_cast<const f16x8*>(base0 + x1c * 40);
                c10 = *reinterpret_cast<const f16x8*>(base0 + 2560 + x0c * 40);
                c11 = *reinterpret_cast<const f16x8*>(base0 + 2560 + x1c * 40);
            } else {
                int y0c = yy & 0xFF, y1c = (yy >> 8) & 0xFF;
                const _Float16* gb = xb + cq * 32 + oc8;
                c00 = *reinterpret_cast<const f16x8*>(gb + (size_t)(y0c * 64 + x0c) * C_);
                c01 = *reinterpret_cast<const f16x8*>(gb + (size_t)(y0c * 64 + x1c) * C_);
                c10 = *reinterpret_cast<const f16x8*>(gb + (size_t)(y1c * 64 + x0c) * C_);
                c11 = *reinterpret_cast<const f16x8*>(gb + (size_t)(y1c * 64 + x1c) * C_);
            }
            f16x8 pk = c00 * uw0.h[0] + c01 * uw1.h[0] + c10 * uw2.h[0] + c11 * uw3.h[0];

            const f16x8* wf = reinterpret_cast<const f16x8*>(wfrag) +
                              ((size_t)(k2 * 8 + cq) * 16) * 64 + lane;
#pragma unroll
            for (int mf = 0; mf < 16; ++mf) {
                f16x8 af = wf[(size_t)mf * 64];
                acc[mf] = __builtin_amdgcn_mfma_f32_16x16x32_f16(af, pk, acc[mf], 0, 0, 0);
            }
        }

        if (cq < 7) {
            __builtin_amdgcn_s_barrier();  // all waves done reading s_x
            STAGE_WRITE();
            asm volatile("s_waitcnt lgkmcnt(0)" ::: "memory");
            __builtin_amdgcn_s_barrier();  // new chunk visible
        }
    }

    // epilogue: C col = lane&15 (pixel), row = (lane>>4)*4+r (o within frag)
    float* op = out + (size_t)b * O_ * HW_ + h * 64 + wm * 16 + pl;
#pragma unroll
    for (int mf = 0; mf < 16; ++mf)
#pragma unroll
        for (int r = 0; r < 4; ++r) {
            int o = mf * 16 + (lane >> 4) * 4 + r;
            op[(size_t)o * HW_] = acc[mf][r];
        }
}

extern "C" void kernel_launch(void* const* d_in, const int* in_sizes, int n_in,
                              void* d_out, int out_size, void* d_ws, size_t ws_size,
                              hipStream_t stream) {
    const float* x = (const float*)d_in[0];
    const float* w_off = (const float*)d_in[1];
    const float* b_off = (const float*)d_in[2];
    const float* w_def = (const float*)d_in[3];
    float* out = (float*)d_out;
    char* ws = (char*)d_ws;

    float* offs = (float*)ws;                                            // 2,359,296 B
    _Float16* xT = (_Float16*)(ws + 2359296);                            // 16,777,216 B
    _Float16* wfrag = (_Float16*)(ws + 2359296 + 16777216);              // 1,179,648 B
    _Float16* wofr = (_Float16*)(ws + 2359296 + 16777216 + 1179648);     // 147,456 B

    k_nhwc<<<512, 256, 0, stream>>>(x, xT);
    k_prep_wdef<<<288, 256, 0, stream>>>(w_def, wfrag);
    k_prep_woffrag<<<36, 256, 0, stream>>>(w_off, wofr);
    k_offconv4<<<512, 256, 0, stream>>>(xT, wofr, b_off, offs);
    k_deform7<<<512, 256, 0, stream>>>(xT, wfrag, offs, out);
}

// Round 8
// 106.187 us; speedup vs baseline: 1.7907x; 1.7907x over previous
//
#include <hip/hip_runtime.h>
#include <stdint.h>

#define B_ 8
#define C_ 256
#define O_ 256
#define HW_ 4096

typedef _Float16 f16x8 __attribute__((ext_vector_type(8)));
typedef __attribute__((ext_vector_type(4))) float f32x4;

// ---------- prep: x (NCHW f32) -> xT (NHWC fp16, relu applied) ----------
__global__ __launch_bounds__(256) void k_nhwc(const float* __restrict__ x,
                                              _Float16* __restrict__ xT) {
    int bh = blockIdx.x;
    int b = bh & 7, h = bh >> 3;
    int t = threadIdx.x, px = t & 63, wg = t >> 6;
#pragma unroll
    for (int i = 0; i < 4; ++i) {
        int c0 = i * 64 + wg * 16;
        f16x8 va, vb;
#pragma unroll
        for (int j = 0; j < 8; ++j) {
            float f0 = x[((size_t)(b * C_ + c0 + j)) * HW_ + h * 64 + px];
            float f1 = x[((size_t)(b * C_ + c0 + 8 + j)) * HW_ + h * 64 + px];
            va[j] = (_Float16)fmaxf(f0, 0.f);
            vb[j] = (_Float16)fmaxf(f1, 0.f);
        }
        _Float16* dst = xT + ((size_t)((b * 64 + h) * 64 + px)) * C_ + c0;
        *reinterpret_cast<f16x8*>(dst) = va;
        *reinterpret_cast<f16x8*>(dst + 8) = vb;
    }
}

// ---------- prep: w_def -> fp16 MFMA A-frags [k2][q8][mfg16][lane64][8] ----------
__global__ void k_prep_wdef(const float* __restrict__ w_def, _Float16* __restrict__ wfrag) {
    int idx = blockIdx.x * 256 + threadIdx.x;
    if (idx >= 9 * 8 * 16 * 64) return;
    int lane = idx & 63;
    int mfg = (idx >> 6) & 15;
    int ccc = (idx >> 10) & 7;
    int k2 = idx >> 13;
    int o = mfg * 16 + (lane & 15);
    int cb = ccc * 32 + (lane >> 4) * 8;
    f16x8 pk;
#pragma unroll
    for (int j = 0; j < 8; ++j)
        pk[j] = (_Float16)w_def[(size_t)(o * C_ + cb + j) * 9 + k2];
    *reinterpret_cast<f16x8*>(wfrag + (size_t)idx * 8) = pk;
}

// ---------- prep: w_off -> fp16 MFMA A-frags (M pad 18->32) ----------
__global__ void k_prep_woffrag(const float* __restrict__ w_off, _Float16* __restrict__ wfr) {
    int idx = blockIdx.x * 256 + threadIdx.x;
    if (idx >= 9 * 8 * 2 * 64) return;
    int lane = idx & 63;
    int mfg = (idx >> 6) & 1;
    int ccc = (idx >> 7) & 7;
    int k2 = idx >> 10;
    int o = mfg * 16 + (lane & 15);
    int cb = ccc * 32 + (lane >> 4) * 8;
    f16x8 pk;
#pragma unroll
    for (int j = 0; j < 8; ++j)
        pk[j] = (o < 18) ? (_Float16)w_off[(size_t)(o * C_ + cb + j) * 9 + k2] : (_Float16)0.f;
    *reinterpret_cast<f16x8*>(wfr + (size_t)idx * 8) = pk;
}

// ---------- offset conv via MFMA, no LDS ----------
__global__ __launch_bounds__(256) void k_offconv4(const _Float16* __restrict__ xT,
                                                  const _Float16* __restrict__ wofr,
                                                  const float* __restrict__ b_off,
                                                  float* __restrict__ offs) {
    int bh = blockIdx.x;
    int b = bh & 7, h = bh >> 3;
    int tid = threadIdx.x, lane = tid & 63, wm = tid >> 6;
    int px = wm * 16 + (lane & 15);
    int chl = (lane >> 4) * 8;
    f32x4 acc0 = (f32x4){0.f, 0.f, 0.f, 0.f};
    f32x4 acc1 = (f32x4){0.f, 0.f, 0.f, 0.f};
    const _Float16* xb = xT + (size_t)b * HW_ * C_;
    for (int k2 = 0; k2 < 9; ++k2) {
        int y = h + k2 / 3 - 1;
        int xs = px + k2 % 3 - 1;
        bool v = ((unsigned)y < 64u) && ((unsigned)xs < 64u);
        int yc = y < 0 ? 0 : (y > 63 ? 63 : y);
        int xc = xs < 0 ? 0 : (xs > 63 ? 63 : xs);
        const _Float16* xp = xb + (size_t)(yc * 64 + xc) * C_ + chl;
#pragma unroll
        for (int q = 0; q < 8; ++q) {
            f16x8 bf = *reinterpret_cast<const f16x8*>(xp + q * 32);
            if (!v) bf = (f16x8)(_Float16)0.f;
            const f16x8* wp = reinterpret_cast<const f16x8*>(wofr) +
                              (size_t)((k2 * 8 + q) * 2) * 64 + lane;
            acc0 = __builtin_amdgcn_mfma_f32_16x16x32_f16(wp[0], bf, acc0, 0, 0, 0);
            acc1 = __builtin_amdgcn_mfma_f32_16x16x32_f16(wp[64], bf, acc1, 0, 0, 0);
        }
    }
#pragma unroll
    for (int r = 0; r < 4; ++r) {
        int oc = (lane >> 4) * 4 + r;
        offs[(((size_t)b * 18 + oc) * 64 + h) * 64 + px] = acc0[r] + b_off[oc];
    }
#pragma unroll
    for (int r = 0; r < 4; ++r) {
        int oc = 16 + (lane >> 4) * 4 + r;
        if (oc < 18)
            offs[(((size_t)b * 18 + oc) * 64 + h) * 64 + px] = acc1[r] + b_off[oc];
    }
}

// ---------- deform v8: v6 skeleton + one-time geometry precompute in LDS ----------
// Block (b,h): wave wm owns M-rows [wm*64, wm*64+64). K = 8 chunks(32ch) x 9 taps.
// Pack role: thread = (pixel gp = tid&63, octet gq = tid>>6).
__global__ __launch_bounds__(256, 2) void k_deform8(const _Float16* __restrict__ xT,
                                                    const _Float16* __restrict__ wfrag,
                                                    const float* __restrict__ offs,
                                                    float* __restrict__ out) {
    int blk = blockIdx.x;
    int b = blk & 7, h = blk >> 3;
    int tid = threadIdx.x, lane = tid & 63, wm = tid >> 6;
    int gp = tid & 63, gq = tid >> 6;

    // geo.x = w00|w01 (f16), geo.y = w10|w11 (f16), geo.z = x0c|x1c<<16,
    // geo.w = y0c | y1c<<8 | flag<<16 (flag = ry0 in [0,5], else 255)
    __shared__ uint4 s_geo[576];
    __shared__ __align__(16) _Float16 s_x[7 * 64 * 40];    // rows h-3..h+3, 80B px-stride
    __shared__ __align__(16) _Float16 s_samp[2][64 * 40];  // ping-pong [px][4 octets]

    const _Float16* xb = xT + (size_t)b * HW_ * C_;

    // ---- stage chunk 0 loads first (in flight under geometry compute) ----
    int spx = tid >> 2, so = tid & 3;
    f16x8 st[7];
#define STAGE_LOAD(CQ)                                                             \
    {                                                                              \
        _Pragma("unroll") for (int r = 0; r < 7; ++r)                              \
        {                                                                          \
            int yr = h - 3 + r;                                                    \
            yr = yr < 0 ? 0 : (yr > 63 ? 63 : yr);                                 \
            st[r] = *reinterpret_cast<const f16x8*>(                               \
                xb + (size_t)(yr * 64 + spx) * C_ + (CQ) * 32 + so * 8);           \
        }                                                                          \
    }
#define STAGE_WRITE()                                                              \
    {                                                                              \
        _Pragma("unroll") for (int r = 0; r < 7; ++r)                              \
            *reinterpret_cast<f16x8*>(&s_x[(r * 64 + spx) * 40 + so * 8]) = st[r]; \
    }

    STAGE_LOAD(0);

    // ---- phase 0: geometry (once per block) ----
    for (int idx = tid; idx < 576; idx += 256) {
        int k2 = idx >> 6, p = idx & 63;
        float dy = offs[(((size_t)b * 18 + k2 * 2 + 0) * 64 + h) * 64 + p];
        float dx = offs[(((size_t)b * 18 + k2 * 2 + 1) * 64 + h) * 64 + p];
        float py = (float)(h - 1 + k2 / 3) + dy;
        float pxx = (float)(p - 1 + k2 % 3) + dx;
        float y0f = floorf(py), x0f = floorf(pxx);
        float wy = py - y0f, wx = pxx - x0f;
        int y0 = (int)y0f, x0 = (int)x0f;
        float w00 = (1.f - wy) * (1.f - wx), w01 = (1.f - wy) * wx;
        float w10 = wy * (1.f - wx), w11 = wy * wx;
        bool vy0 = (unsigned)y0 < 64u, vy1 = (unsigned)(y0 + 1) < 64u;
        bool vx0 = (unsigned)x0 < 64u, vx1 = (unsigned)(x0 + 1) < 64u;
        if (!(vy0 && vx0)) w00 = 0.f;
        if (!(vy0 && vx1)) w01 = 0.f;
        if (!(vy1 && vx0)) w10 = 0.f;
        if (!(vy1 && vx1)) w11 = 0.f;
        union { _Float16 h[2]; unsigned u; } p01, p23;
        p01.h[0] = (_Float16)w00; p01.h[1] = (_Float16)w01;
        p23.h[0] = (_Float16)w10; p23.h[1] = (_Float16)w11;
        int x0c = x0 < 0 ? 0 : (x0 > 63 ? 63 : x0);
        int x1c = (x0 + 1) < 0 ? 0 : ((x0 + 1) > 63 ? 63 : (x0 + 1));
        int y0c = y0 < 0 ? 0 : (y0 > 63 ? 63 : y0);
        int y1c = (y0 + 1) < 0 ? 0 : ((y0 + 1) > 63 ? 63 : (y0 + 1));
        int ry0 = y0 - (h - 3);
        unsigned flag = (ry0 >= 0 && ry0 <= 5) ? (unsigned)ry0 : 255u;
        uint4 g;
        g.x = p01.u;
        g.y = p23.u;
        g.z = (unsigned)x0c | ((unsigned)x1c << 16);
        g.w = (unsigned)y0c | ((unsigned)y1c << 8) | (flag << 16);
        s_geo[idx] = g;
    }

    STAGE_WRITE();
    asm volatile("s_waitcnt lgkmcnt(0)" ::: "memory");
    __builtin_amdgcn_s_barrier();

    f32x4 acc[4][4];
#pragma unroll
    for (int i = 0; i < 4; ++i)
#pragma unroll
        for (int j = 0; j < 4; ++j) acc[i][j] = (f32x4){0.f, 0.f, 0.f, 0.f};

#define LOADA(DST, T)                                                              \
    {                                                                              \
        const f16x8* wf = reinterpret_cast<const f16x8*>(wfrag) +                  \
                          ((size_t)(T) * 16 + wm * 4) * 64 + lane;                 \
        _Pragma("unroll") for (int mf = 0; mf < 4; ++mf) DST[mf] = wf[mf * 64];    \
    }

#define PACKSTEP(K2, BUF, CQ)                                                      \
    {                                                                              \
        uint4 gg = s_geo[(K2) * 64 + gp];                                          \
        union { unsigned u; _Float16 h[2]; } p01, p23;                             \
        p01.u = gg.x; p23.u = gg.y;                                                \
        int x0c = gg.z & 0xFFFF, x1c = gg.z >> 16;                                 \
        int flag = gg.w >> 16;                                                     \
        f16x8 c00, c01, c10, c11;                                                  \
        if (flag <= 5) {                                                           \
            const _Float16* base0 = s_x + flag * 2560 + gq * 8;                    \
            c00 = *reinterpret_cast<const f16x8*>(base0 + x0c * 40);               \
            c01 = *reinterpret_cast<const f16x8*>(base0 + x1c * 40);               \
            c10 = *reinterpret_cast<const f16x8*>(base0 + 2560 + x0c * 40);        \
            c11 = *reinterpret_cast<const f16x8*>(base0 + 2560 + x1c * 40);        \
        } else {                                                                   \
            int y0c = gg.w & 0xFF, y1c = (gg.w >> 8) & 0xFF;                       \
            const _Float16* gb = xb + (CQ) * 32 + gq * 8;                          \
            c00 = *reinterpret_cast<const f16x8*>(gb + (size_t)(y0c * 64 + x0c) * C_); \
            c01 = *reinterpret_cast<const f16x8*>(gb + (size_t)(y0c * 64 + x1c) * C_); \
            c10 = *reinterpret_cast<const f16x8*>(gb + (size_t)(y1c * 64 + x0c) * C_); \
            c11 = *reinterpret_cast<const f16x8*>(gb + (size_t)(y1c * 64 + x1c) * C_); \
        }                                                                          \
        f16x8 pk = c00 * p01.h[0] + c01 * p01.h[1] + c10 * p23.h[0] + c11 * p23.h[1]; \
        *reinterpret_cast<f16x8*>(&s_samp[BUF][gp * 40 + gq * 8]) = pk;            \
    }

    f16x8 Ac[4], An[4];
    LOADA(Ac, 0);
#pragma unroll
    for (int mf = 0; mf < 4; ++mf) An[mf] = Ac[mf];

    for (int cq = 0; cq < 8; ++cq) {
        PACKSTEP(0, 0, cq);  // tap 0 into buf 0
        asm volatile("s_waitcnt lgkmcnt(0)" ::: "memory");
        __builtin_amdgcn_s_barrier();

        if (cq < 7) STAGE_LOAD(cq + 1);  // next chunk's rows: in flight under 9 taps

#pragma unroll
        for (int k2 = 0; k2 < 9; ++k2) {
            if (k2 < 8) {
                LOADA(An, (k2 + 1) * 8 + cq);
            } else if (cq < 7) {
                LOADA(An, cq + 1);
            }

            f16x8 bfr[4];
#pragma unroll
            for (int nf = 0; nf < 4; ++nf) {
                int n = nf * 16 + (lane & 15);
                bfr[nf] = *reinterpret_cast<const f16x8*>(
                    &s_samp[k2 & 1][n * 40 + (lane >> 4) * 8]);
            }

#pragma unroll
            for (int mf = 0; mf < 4; ++mf)
#pragma unroll
                for (int nf = 0; nf < 4; ++nf)
                    acc[mf][nf] = __builtin_amdgcn_mfma_f32_16x16x32_f16(
                        Ac[mf], bfr[nf], acc[mf][nf], 0, 0, 0);

            if (k2 < 8) PACKSTEP(k2 + 1, (k2 + 1) & 1, cq);
#pragma unroll
            for (int mf = 0; mf < 4; ++mf) Ac[mf] = An[mf];

            asm volatile("s_waitcnt lgkmcnt(0)" ::: "memory");
            __builtin_amdgcn_s_barrier();
        }

        if (cq < 7) {
            STAGE_WRITE();  // s_x free to overwrite: all taps of this chunk done
            asm volatile("s_waitcnt lgkmcnt(0)" ::: "memory");
            __builtin_amdgcn_s_barrier();
        }
    }

    float* op = out + (size_t)b * O_ * HW_ + h * 64;
#pragma unroll
    for (int mf = 0; mf < 4; ++mf)
#pragma unroll
        for (int nf = 0; nf < 4; ++nf)
#pragma unroll
            for (int r = 0; r < 4; ++r) {
                int o = wm * 64 + mf * 16 + (lane >> 4) * 4 + r;
                int w = nf * 16 + (lane & 15);
                op[(size_t)o * HW_ + w] = acc[mf][nf][r];
            }
}

extern "C" void kernel_launch(void* const* d_in, const int* in_sizes, int n_in,
                              void* d_out, int out_size, void* d_ws, size_t ws_size,
                              hipStream_t stream) {
    const float* x = (const float*)d_in[0];
    const float* w_off = (const float*)d_in[1];
    const float* b_off = (const float*)d_in[2];
    const float* w_def = (const float*)d_in[3];
    float* out = (float*)d_out;
    char* ws = (char*)d_ws;

    float* offs = (float*)ws;                                            // 2,359,296 B
    _Float16* xT = (_Float16*)(ws + 2359296);                            // 16,777,216 B
    _Float16* wfrag = (_Float16*)(ws + 2359296 + 16777216);              // 1,179,648 B
    _Float16* wofr = (_Float16*)(ws + 2359296 + 16777216 + 1179648);     // 147,456 B

    k_nhwc<<<512, 256, 0, stream>>>(x, xT);
    k_prep_wdef<<<288, 256, 0, stream>>>(w_def, wfrag);
    k_prep_woffrag<<<36, 256, 0, stream>>>(w_off, wofr);
    k_offconv4<<<512, 256, 0, stream>>>(xT, wofr, b_off, offs);
    k_deform8<<<512, 256, 0, stream>>>(xT, wfrag, offs, out);
}